// Round 13
// baseline (304.735 us; speedup 1.0000x reference)
//
#include <hip/hip_runtime.h>

typedef float  f32x4 __attribute__((ext_vector_type(4)));
typedef int    i32x4 __attribute__((ext_vector_type(4)));
typedef short  s16x8 __attribute__((ext_vector_type(8)));
typedef short  s16x4 __attribute__((ext_vector_type(4)));
typedef unsigned short u16;

#define HDIM 1024
#define BATCH 32
#define SEQ 2048
#define NROWS (BATCH*SEQ)   // 65536
#define GSEQ 8192           // 4 batches per compaction group
#define NGRP 8

// k_score: 256x256 tile, BK=32, 8 waves (2M x 4N), 512 threads (R3 champion)
#define BM 256
#define BN 256
#define BK 32
#define NKT (HDIM/BK)       // 32

#define GLD16(gp, lp) __builtin_amdgcn_global_load_lds( \
    (const __attribute__((address_space(1))) void*)(gp), \
    (__attribute__((address_space(3))) void*)(lp), 16, 0, 0)

#define VMCNT(n) asm volatile("s_waitcnt vmcnt(" #n ")" ::: "memory")
#define LGKM0    asm volatile("s_waitcnt lgkmcnt(0)" ::: "memory")
#define BARRIER  asm volatile("s_barrier" ::: "memory")
#define SCHEDB   __builtin_amdgcn_sched_barrier(0)

__device__ __forceinline__ u16 f2bf(float f){
    unsigned u = __float_as_uint(f);
    u = u + 0x7FFFu + ((u >> 16) & 1u);   // RNE
    return (u16)(u >> 16);
}

__device__ __forceinline__ float tanh_fast(float x){
    float e = __builtin_amdgcn_exp2f(x * 2.885390082f);
    return 1.0f - 2.0f * __builtin_amdgcn_rcpf(e + 1.0f);
}

// ---------------- setup: W1T transpose | qproj | mask group-scan + ctr zero ------
// blocks [0,256) w1t; [256,768) qproj; [768,776) mask scan (1 per 4-batch group).
__global__ __launch_bounds__(256) void k_setup(const float* __restrict__ W1,
                                               u16* __restrict__ W1T,
                                               const float* __restrict__ query,
                                               const float* __restrict__ W2,
                                               float* __restrict__ qproj,
                                               const int* __restrict__ mask,
                                               int* __restrict__ cnt4,
                                               int* __restrict__ off,
                                               int* __restrict__ idx,
                                               int* __restrict__ pos,
                                               int* __restrict__ ctr){
    __shared__ u16 tsh[64][65];
    __shared__ float red[4][64];
    __shared__ int ps[256];
    int blk = blockIdx.x;
    int tid = threadIdx.x;

    if (blk < 256){
        // ---- W1 -> W1T (bf16, transposed) ----
        int bh = blk >> 4, bd = blk & 15;
        int h0 = bh * 64, d0 = bd * 64;
        int lh = tid >> 4, ld = (tid & 15) * 4;
#pragma unroll
        for (int i = 0; i < 4; ++i){
            int hh = lh + i * 16;
            f32x4 v = *(const f32x4*)&W1[(size_t)(h0 + hh) * HDIM + d0 + ld];
            tsh[hh][ld + 0] = f2bf(v.x);
            tsh[hh][ld + 1] = f2bf(v.y);
            tsh[hh][ld + 2] = f2bf(v.z);
            tsh[hh][ld + 3] = f2bf(v.w);
        }
        __syncthreads();
        int wv = tid >> 6, ln = tid & 63;
#pragma unroll
        for (int i = 0; i < 16; ++i){
            int d = i * 4 + wv;
            W1T[(size_t)(d0 + d) * HDIM + h0 + ln] = tsh[ln][d];
        }
    } else if (blk < 768){
        // ---- qproj[b][d] = sum_h query[b][h] * W2[h][d] ----
        int blk2 = blk - 256;
        int b = blk2 >> 4, dc = blk2 & 15;
        int dl = tid & 63, hq = tid >> 6;
        int d = dc * 64 + dl;
        const float* q = query + (size_t)b * HDIM;
        float acc = 0.f;
#pragma unroll 8
        for (int h = hq * 256; h < hq * 256 + 256; ++h)
            acc += q[h] * W2[(size_t)h * HDIM + d];
        red[hq][dl] = acc;
        __syncthreads();
        if (hq == 0)
            qproj[(size_t)b * HDIM + d] = red[0][dl] + red[1][dl] + red[2][dl] + red[3][dl];
    } else {
        // ---- mask scan for group g: cnt4, off[4], idx, pos; g==0 zeroes ctr ----
        int g = blk - 768;
        if (g == 0 && tid < BATCH) ctr[tid] = 0;     // deterministic per-launch init
        const int* mb = mask + (size_t)g * GSEQ;
        unsigned bits = 0;
#pragma unroll
        for (int i = 0; i < 8; ++i){
            i32x4 v = ((const i32x4*)mb)[tid * 8 + i];
            bits |= (unsigned)(v.x != 0) << (i * 4 + 0);
            bits |= (unsigned)(v.y != 0) << (i * 4 + 1);
            bits |= (unsigned)(v.z != 0) << (i * 4 + 2);
            bits |= (unsigned)(v.w != 0) << (i * 4 + 3);
        }
        int s = __popc(bits);
        ps[tid] = s;
        __syncthreads();
        for (int o = 1; o < 256; o <<= 1){
            int v = (tid >= o) ? ps[tid - o] : 0;
            __syncthreads();
            ps[tid] += v;
            __syncthreads();
        }
        int run = ps[tid] - s;               // exclusive prefix at elem tid*32
        if (tid == 255) cnt4[g] = ps[255];
        if ((tid & 63) == 0) off[g * 4 + (tid >> 6)] = run;   // batch starts at 2048j
        for (int i = 0; i < 32; ++i){
            if ((bits >> i) & 1u){
                int slot = run + __popc(bits & ((1u << i) - 1u));
                int so = tid * 32 + i;
                idx[(size_t)g * GSEQ + slot] = so;
                pos[(size_t)g * GSEQ + so]  = slot;
            }
        }
    }
}

// ---------------- gather-convert unmasked keys fp32 -> group-compact bf16 --------
__global__ __launch_bounds__(256) void k_gather(const float* __restrict__ keys,
                                                const int* __restrict__ cnt4,
                                                const int* __restrict__ idx,
                                                u16* __restrict__ keysbf){
    int blk = blockIdx.x;                 // 8192 = 8 groups x 1024 chunks
    int g = blk >> 10, chunk = blk & 1023;
    int n = cnt4[g];
    int base = chunk * 8;
    if (base >= n) return;
    int t = threadIdx.x;
    int j = t >> 5, l = t & 31;
    int slot = base + j;
    if (slot >= n) return;                // no barriers below: divergence safe
    int orig = idx[(size_t)g * GSEQ + slot];
    const float* src = keys + ((size_t)g * GSEQ + orig) * HDIM + l * 4;
    u16* dst = keysbf + ((size_t)g * GSEQ + slot) * HDIM + l * 4;
#pragma unroll
    for (int i = 0; i < 8; ++i){
        f32x4 v = *(const f32x4*)(src + i * 128);
        s16x4 o;
        o[0] = (short)f2bf(v.x); o[1] = (short)f2bf(v.y);
        o[2] = (short)f2bf(v.z); o[3] = (short)f2bf(v.w);
        *(s16x4*)(dst + i * 128) = o;
    }
}

// ---------------- scores GEMM: R3 champion + group-compact early exit ------------
__global__ __launch_bounds__(512, 2) void k_score(const u16* __restrict__ keysbf,
                                                  const u16* __restrict__ W1T,
                                                  const float* __restrict__ qproj,
                                                  const float* __restrict__ V,
                                                  const int* __restrict__ cnt4,
                                                  const int* __restrict__ off,
                                                  float* __restrict__ spart){
    int bid = blockIdx.x;
    int lid = (bid & 7) * 128 + (bid >> 3);   // XCD swizzle
    int gb  = lid >> 7;                        // group 0..7
    int r7  = lid & 127;
    int mtl = r7 >> 2;                         // 0..31 within group
    int nt  = r7 & 3;
    if (mtl * 256 >= cnt4[gb]) return;         // uniform: tile fully beyond cnt

    __shared__ u16 As[2][BM * BK];
    __shared__ u16 Bs[2][BM * BK];

    int tid  = threadIdx.x;
    int lane = tid & 63, wave = tid >> 6;
    int wm = wave >> 2, wn = wave & 3;
    int lg = lane >> 4, q = lane & 15;

    int sr = tid >> 2, sl = tid & 3;
    int ch = sl ^ ((sr >> 1) & 3);
    const u16* asrc = keysbf + ((size_t)gb * GSEQ + mtl * BM + sr) * HDIM + ch * 8;
    const u16* bsrc = W1T    + (size_t)(nt * BN + sr) * HDIM + ch * 8;
    int dst = tid * 8;

    auto stage = [&](int buf, int kt){
        int ko = kt * BK;
        GLD16(asrc + ko,               &As[buf][dst]);
        GLD16(asrc + ko + 128 * HDIM,  &As[buf][dst + 128 * BK]);
        GLD16(bsrc + ko,               &Bs[buf][dst]);
        GLD16(bsrc + ko + 128 * HDIM,  &Bs[buf][dst + 128 * BK]);
    };

    int slotx = (q >> 1) & 3;
    int rslot = (lg ^ slotx) * 8;
    int aoff = (wm * 128 + q) * BK + rslot;
    int boff = (wn * 64 + q) * BK + rslot;

    f32x4 acc[8][4];
#pragma unroll
    for (int m = 0; m < 8; ++m)
#pragma unroll
        for (int n = 0; n < 4; ++n) acc[m][n] = 0.f;

    stage(0, 0);
    stage(1, 1);
    VMCNT(4);
    SCHEDB;
    BARRIER;
    SCHEDB;

    for (int kt = 0; kt < NKT; ++kt){
        int cur = kt & 1;
        s16x8 af[8], bq[4];
#pragma unroll
        for (int m = 0; m < 8; ++m) af[m] = *(const s16x8*)&As[cur][aoff + m * 16 * BK];
#pragma unroll
        for (int n = 0; n < 4; ++n) bq[n] = *(const s16x8*)&Bs[cur][boff + n * 16 * BK];

        __builtin_amdgcn_s_setprio(1);
#pragma unroll
        for (int m = 0; m < 8; ++m)
#pragma unroll
            for (int n = 0; n < 4; ++n)
                acc[m][n] = __builtin_amdgcn_mfma_f32_16x16x32_bf16(af[m], bq[n], acc[m][n], 0, 0, 0);
        __builtin_amdgcn_s_setprio(0);

        SCHEDB;
        LGKM0;
        BARRIER;
        SCHEDB;
        stage(cur, (kt + 2 < NKT) ? kt + 2 : NKT - 1);
        VMCNT(4);
        SCHEDB;
        BARRIER;
        SCHEDB;
    }
    VMCNT(0);

    // ---- epilogue with per-row batch-select qproj ----
    int o1 = off[gb * 4 + 1], o2 = off[gb * 4 + 2], o3 = off[gb * 4 + 3];
    float Vn[4], Q0[4], Q1[4], Q2[4], Q3[4];
#pragma unroll
    for (int n = 0; n < 4; ++n){
        int D = nt * BN + wn * 64 + n * 16 + q;
        Vn[n] = V[D];
        Q0[n] = qproj[(size_t)(gb * 4 + 0) * HDIM + D];
        Q1[n] = qproj[(size_t)(gb * 4 + 1) * HDIM + D];
        Q2[n] = qproj[(size_t)(gb * 4 + 2) * HDIM + D];
        Q3[n] = qproj[(size_t)(gb * 4 + 3) * HDIM + D];
    }
#pragma unroll
    for (int m = 0; m < 8; ++m){
#pragma unroll
        for (int r = 0; r < 4; ++r){
            int loc = mtl * BM + wm * 128 + m * 16 + lg * 4 + r;  // compact slot
            float s = 0.f;
#pragma unroll
            for (int n = 0; n < 4; ++n){
                float Qn = Q0[n];
                Qn = (loc >= o1) ? Q1[n] : Qn;
                Qn = (loc >= o2) ? Q2[n] : Qn;
                Qn = (loc >= o3) ? Q3[n] : Qn;
                float x = acc[m][n][r] + Qn;
                s += Vn[n] * tanh_fast(x);
            }
            s += __shfl_xor(s, 1);
            s += __shfl_xor(s, 2);
            s += __shfl_xor(s, 4);
            s += __shfl_xor(s, 8);
            if (q == 0)
                spart[((size_t)gb * GSEQ + loc) * 16 + nt * 4 + wn] = s;
        }
    }
}

// ---------------- softmax over S per batch (1024 threads, 2 elems/thread) --------
__global__ __launch_bounds__(1024) void k_softmax(const float* __restrict__ spart,
                                                  const int* __restrict__ mask,
                                                  const int* __restrict__ pos,
                                                  float* __restrict__ attn){
    int b = blockIdx.x;
    int gb = b >> 2;
    int tid = threadIdx.x;
    int lane = tid & 63, wv = tid >> 6;
    __shared__ float redmx[16];
    __shared__ float redsm[16];

    float sc[2];
#pragma unroll
    for (int i = 0; i < 2; ++i){
        int s = i * 1024 + tid;
        int mk = mask[(size_t)b * SEQ + s];
        if (mk != 0){
            int p = pos[(size_t)b * SEQ + s];    // slot within group
            const f32x4* pp = (const f32x4*)&spart[((size_t)gb * GSEQ + p) * 16];
            f32x4 v0 = pp[0], v1 = pp[1], v2 = pp[2], v3 = pp[3];
            sc[i] = (v0.x + v0.y + v0.z + v0.w) + (v1.x + v1.y + v1.z + v1.w)
                  + (v2.x + v2.y + v2.z + v2.w) + (v3.x + v3.y + v3.z + v3.w);
        } else {
            sc[i] = -1e9f;
        }
    }
    float mx = fmaxf(sc[0], sc[1]);
#pragma unroll
    for (int o = 32; o >= 1; o >>= 1) mx = fmaxf(mx, __shfl_xor(mx, o));
    if (lane == 0) redmx[wv] = mx;
    __syncthreads();
    mx = redmx[0];
#pragma unroll
    for (int i = 1; i < 16; ++i) mx = fmaxf(mx, redmx[i]);

    float ex[2];
    ex[0] = __builtin_amdgcn_exp2f((sc[0] - mx) * 1.4426950408889634f);
    ex[1] = __builtin_amdgcn_exp2f((sc[1] - mx) * 1.4426950408889634f);
    float ssum = ex[0] + ex[1];
#pragma unroll
    for (int o = 32; o >= 1; o >>= 1) ssum += __shfl_xor(ssum, o);
    if (lane == 0) redsm[wv] = ssum;
    __syncthreads();
    ssum = redsm[0];
#pragma unroll
    for (int i = 1; i < 16; ++i) ssum += redsm[i];
    float inv = 1.0f / ssum;
    attn[(size_t)b * SEQ + tid]        = ex[0] * inv;
    attn[(size_t)b * SEQ + 1024 + tid] = ex[1] * inv;
}

// ---------------- context: partials + last-block-per-batch final reduce ----------
__global__ __launch_bounds__(256) void k_ctxpart(const u16* __restrict__ keysbf,
                                                 const float* __restrict__ attn,
                                                 const int* __restrict__ cnt4,
                                                 const int* __restrict__ off,
                                                 const int* __restrict__ idx,
                                                 float* __restrict__ cpart,
                                                 int* __restrict__ ctr,
                                                 float* __restrict__ ctx){
    int blk = blockIdx.x;                 // 1024 = 32 b x 32 slices
    int b = blk >> 5, scn = blk & 31;
    int gb = b >> 2, j = b & 3;
    int oj  = off[gb * 4 + j];
    int oj1 = (j < 3) ? off[gb * 4 + j + 1] : cnt4[gb];
    int nb  = oj1 - oj;                   // rows of this batch
    int lim = nb - scn * 64;
    if (lim > 64) lim = 64;
    int t = threadIdx.x;
    f32x4 acc = 0.f;
    size_t base = (size_t)gb * GSEQ + oj + scn * 64;
    const s16x4* kp = (const s16x4*)(keysbf + base * HDIM) + t;
    const int* ip = idx + base;
    for (int s = 0; s < lim; ++s){
        float a = attn[(size_t)gb * GSEQ + ip[s]];
        s16x4 kv = kp[(size_t)s * 256];
        f32x4 kf;
        kf.x = __uint_as_float((unsigned)(unsigned short)kv[0] << 16);
        kf.y = __uint_as_float((unsigned)(unsigned short)kv[1] << 16);
        kf.z = __uint_as_float((unsigned)(unsigned short)kv[2] << 16);
        kf.w = __uint_as_float((unsigned)(unsigned short)kv[3] << 16);
        acc += a * kf;
    }
    // always write (zeros when lim<=0) so the reducer sums no garbage
    *(f32x4*)&cpart[(size_t)(b * 32 + scn) * HDIM + t * 4] = acc;

    // ---- last block of this batch reduces the 32 slices (device-scope) ----
    __threadfence();                          // release: cpart visible device-wide
    __shared__ int lastblk;
    if (t == 0) lastblk = (atomicAdd(&ctr[b], 1) == 31);
    __syncthreads();
    if (lastblk){
        __threadfence();                      // acquire: see all 32 slices
        f32x4 s = 0.f;
#pragma unroll
        for (int sc = 0; sc < 32; ++sc)
            s += *(const f32x4*)&cpart[(size_t)(b * 32 + sc) * HDIM + t * 4];
        *(f32x4*)&ctx[(size_t)b * HDIM + t * 4] = s;
    }
}

// ---------------- launch ---------------------------------------------------------
extern "C" void kernel_launch(void* const* d_in, const int* in_sizes, int n_in,
                              void* d_out, int out_size, void* d_ws, size_t ws_size,
                              hipStream_t stream){
    (void)in_sizes; (void)n_in; (void)out_size; (void)ws_size;
    const float* query = (const float*)d_in[0];
    const float* keys  = (const float*)d_in[1];
    const int*   mask  = (const int*)d_in[2];
    const float* W1    = (const float*)d_in[3];
    const float* W2    = (const float*)d_in[4];
    const float* V     = (const float*)d_in[5];

    float* ctx_out  = (float*)d_out;            // [32][1024]
    float* attn_out = ctx_out + BATCH * HDIM;   // [32][2048]

    char* ws = (char*)d_ws;
    u16*   W1T   = (u16*)ws;                                   // 2 MB   @ 0
    float* qproj = (float*)(ws + (2u << 20));                  // 128 KB @ 2M
    int*   cnt4  = (int*)  (ws + (2u << 20) + (128u << 10));   // 32 B
    int*   off   = (int*)  (ws + (2u << 20) + (132u << 10));   // 128 B
    int*   ctr   = (int*)  (ws + (2u << 20) + (136u << 10));   // 128 B
    int*   idx   = (int*)  (ws + (2u << 20) + (512u << 10));   // 256 KB @ 2.5M
    int*   pos   = (int*)  (ws + (3u << 20));                  // 256 KB @ 3M
    float* spart = (float*)(ws + (4u << 20));                  // 4 MB   @ 4M
    float* cpart = spart;   // reuse (spart dead after softmax)
    u16*   keysbf= (u16*)(ws + (9u << 20));                    // 128 MB @ 9M

    k_setup  <<<dim3(776),  dim3(256),  0, stream>>>(W1, W1T, query, W2, qproj,
                                                     mask, cnt4, off, idx, pos, ctr);
    k_gather <<<dim3(8192), dim3(256),  0, stream>>>(keys, cnt4, idx, keysbf);
    k_score  <<<dim3(1024), dim3(512),  0, stream>>>(keysbf, W1T, qproj, V,
                                                     cnt4, off, spart);
    k_softmax<<<dim3(32),   dim3(1024), 0, stream>>>(spart, mask, pos, attn_out);
    k_ctxpart<<<dim3(1024), dim3(256),  0, stream>>>(keysbf, attn_out, cnt4, off,
                                                     idx, cpart, ctr, ctx_out);
}

// Round 14
// 197.076 us; speedup vs baseline: 1.5463x; 1.5463x over previous
//
#include <hip/hip_runtime.h>

typedef float  f32x4 __attribute__((ext_vector_type(4)));
typedef int    i32x4 __attribute__((ext_vector_type(4)));
typedef short  s16x8 __attribute__((ext_vector_type(8)));
typedef short  s16x4 __attribute__((ext_vector_type(4)));
typedef unsigned short u16;

#define HDIM 1024
#define BATCH 32
#define SEQ 2048
#define NROWS (BATCH*SEQ)   // 65536
#define GSEQ 8192           // 4 batches per compaction group
#define NGRP 8

// k_score: 256x256 tile, BK=32, 8 waves (2M x 4N), 512 threads (R3 champion)
#define BM 256
#define BN 256
#define BK 32
#define NKT (HDIM/BK)       // 32

#define GLD16(gp, lp) __builtin_amdgcn_global_load_lds( \
    (const __attribute__((address_space(1))) void*)(gp), \
    (__attribute__((address_space(3))) void*)(lp), 16, 0, 0)

#define VMCNT(n) asm volatile("s_waitcnt vmcnt(" #n ")" ::: "memory")
#define LGKM0    asm volatile("s_waitcnt lgkmcnt(0)" ::: "memory")
#define BARRIER  asm volatile("s_barrier" ::: "memory")
#define SCHEDB   __builtin_amdgcn_sched_barrier(0)

__device__ __forceinline__ u16 f2bf(float f){
    unsigned u = __float_as_uint(f);
    u = u + 0x7FFFu + ((u >> 16) & 1u);   // RNE
    return (u16)(u >> 16);
}

__device__ __forceinline__ float tanh_fast(float x){
    float e = __builtin_amdgcn_exp2f(x * 2.885390082f);
    return 1.0f - 2.0f * __builtin_amdgcn_rcpf(e + 1.0f);
}

// ---------------- setup: W1T transpose | qproj | mask group-scan -----------------
// blocks [0,256) w1t; [256,768) qproj; [768,776) mask scan (1 per 4-batch group).
__global__ __launch_bounds__(256) void k_setup(const float* __restrict__ W1,
                                               u16* __restrict__ W1T,
                                               const float* __restrict__ query,
                                               const float* __restrict__ W2,
                                               float* __restrict__ qproj,
                                               const int* __restrict__ mask,
                                               int* __restrict__ cnt4,
                                               int* __restrict__ off,
                                               int* __restrict__ idx,
                                               int* __restrict__ pos){
    __shared__ u16 tsh[64][65];
    __shared__ float red[4][64];
    __shared__ int ps[256];
    int blk = blockIdx.x;
    int tid = threadIdx.x;

    if (blk < 256){
        // ---- W1 -> W1T (bf16, transposed) ----
        int bh = blk >> 4, bd = blk & 15;
        int h0 = bh * 64, d0 = bd * 64;
        int lh = tid >> 4, ld = (tid & 15) * 4;
#pragma unroll
        for (int i = 0; i < 4; ++i){
            int hh = lh + i * 16;
            f32x4 v = *(const f32x4*)&W1[(size_t)(h0 + hh) * HDIM + d0 + ld];
            tsh[hh][ld + 0] = f2bf(v.x);
            tsh[hh][ld + 1] = f2bf(v.y);
            tsh[hh][ld + 2] = f2bf(v.z);
            tsh[hh][ld + 3] = f2bf(v.w);
        }
        __syncthreads();
        int wv = tid >> 6, ln = tid & 63;
#pragma unroll
        for (int i = 0; i < 16; ++i){
            int d = i * 4 + wv;
            W1T[(size_t)(d0 + d) * HDIM + h0 + ln] = tsh[ln][d];
        }
    } else if (blk < 768){
        // ---- qproj[b][d] = sum_h query[b][h] * W2[h][d] ----
        int blk2 = blk - 256;
        int b = blk2 >> 4, dc = blk2 & 15;
        int dl = tid & 63, hq = tid >> 6;
        int d = dc * 64 + dl;
        const float* q = query + (size_t)b * HDIM;
        float acc = 0.f;
#pragma unroll 8
        for (int h = hq * 256; h < hq * 256 + 256; ++h)
            acc += q[h] * W2[(size_t)h * HDIM + d];
        red[hq][dl] = acc;
        __syncthreads();
        if (hq == 0)
            qproj[(size_t)b * HDIM + d] = red[0][dl] + red[1][dl] + red[2][dl] + red[3][dl];
    } else {
        // ---- mask scan for group g: cnt4, off[4], idx (cmp->orig), pos ----
        int g = blk - 768;
        const int* mb = mask + (size_t)g * GSEQ;
        unsigned bits = 0;
#pragma unroll
        for (int i = 0; i < 8; ++i){
            i32x4 v = ((const i32x4*)mb)[tid * 8 + i];
            bits |= (unsigned)(v.x != 0) << (i * 4 + 0);
            bits |= (unsigned)(v.y != 0) << (i * 4 + 1);
            bits |= (unsigned)(v.z != 0) << (i * 4 + 2);
            bits |= (unsigned)(v.w != 0) << (i * 4 + 3);
        }
        int s = __popc(bits);
        ps[tid] = s;
        __syncthreads();
        for (int o = 1; o < 256; o <<= 1){
            int v = (tid >= o) ? ps[tid - o] : 0;
            __syncthreads();
            ps[tid] += v;
            __syncthreads();
        }
        int run = ps[tid] - s;               // exclusive prefix at elem tid*32
        if (tid == 255) cnt4[g] = ps[255];
        if ((tid & 63) == 0) off[g * 4 + (tid >> 6)] = run;   // batch starts at 2048j
        for (int i = 0; i < 32; ++i){
            if ((bits >> i) & 1u){
                int slot = run + __popc(bits & ((1u << i) - 1u));
                int so = tid * 32 + i;
                idx[(size_t)g * GSEQ + slot] = so;
                pos[(size_t)g * GSEQ + so]  = slot;
            }
        }
    }
}

// ---------------- gather-convert unmasked keys fp32 -> group-compact bf16 --------
__global__ __launch_bounds__(256) void k_gather(const float* __restrict__ keys,
                                                const int* __restrict__ cnt4,
                                                const int* __restrict__ idx,
                                                u16* __restrict__ keysbf){
    int blk = blockIdx.x;                 // 8192 = 8 groups x 1024 chunks
    int g = blk >> 10, chunk = blk & 1023;
    int n = cnt4[g];
    int base = chunk * 8;
    if (base >= n) return;
    int t = threadIdx.x;
    int j = t >> 5, l = t & 31;
    int slot = base + j;
    if (slot >= n) return;                // no barriers below: divergence safe
    int orig = idx[(size_t)g * GSEQ + slot];
    const float* src = keys + ((size_t)g * GSEQ + orig) * HDIM + l * 4;
    u16* dst = keysbf + ((size_t)g * GSEQ + slot) * HDIM + l * 4;
#pragma unroll
    for (int i = 0; i < 8; ++i){
        f32x4 v = *(const f32x4*)(src + i * 128);
        s16x4 o;
        o[0] = (short)f2bf(v.x); o[1] = (short)f2bf(v.y);
        o[2] = (short)f2bf(v.z); o[3] = (short)f2bf(v.w);
        *(s16x4*)(dst + i * 128) = o;
    }
}

// ---------------- scores GEMM: R3 champion + group-compact early exit ------------
// Rows are group-compact (4 batches contiguous per group). Epilogue selects the
// per-row qproj bias by comparing the row's compact slot against the group's
// batch offsets (monotone step function; 3 cndmask per row).
__global__ __launch_bounds__(512, 2) void k_score(const u16* __restrict__ keysbf,
                                                  const u16* __restrict__ W1T,
                                                  const float* __restrict__ qproj,
                                                  const float* __restrict__ V,
                                                  const int* __restrict__ cnt4,
                                                  const int* __restrict__ off,
                                                  float* __restrict__ spart){
    int bid = blockIdx.x;
    int lid = (bid & 7) * 128 + (bid >> 3);   // XCD swizzle
    int gb  = lid >> 7;                        // group 0..7
    int r7  = lid & 127;
    int mtl = r7 >> 2;                         // 0..31 within group
    int nt  = r7 & 3;
    if (mtl * 256 >= cnt4[gb]) return;         // uniform: tile fully beyond cnt

    __shared__ u16 As[2][BM * BK];
    __shared__ u16 Bs[2][BM * BK];

    int tid  = threadIdx.x;
    int lane = tid & 63, wave = tid >> 6;
    int wm = wave >> 2, wn = wave & 3;
    int lg = lane >> 4, q = lane & 15;

    int sr = tid >> 2, sl = tid & 3;
    int ch = sl ^ ((sr >> 1) & 3);
    const u16* asrc = keysbf + ((size_t)gb * GSEQ + mtl * BM + sr) * HDIM + ch * 8;
    const u16* bsrc = W1T    + (size_t)(nt * BN + sr) * HDIM + ch * 8;
    int dst = tid * 8;

    auto stage = [&](int buf, int kt){
        int ko = kt * BK;
        GLD16(asrc + ko,               &As[buf][dst]);
        GLD16(asrc + ko + 128 * HDIM,  &As[buf][dst + 128 * BK]);
        GLD16(bsrc + ko,               &Bs[buf][dst]);
        GLD16(bsrc + ko + 128 * HDIM,  &Bs[buf][dst + 128 * BK]);
    };

    int slotx = (q >> 1) & 3;
    int rslot = (lg ^ slotx) * 8;
    int aoff = (wm * 128 + q) * BK + rslot;
    int boff = (wn * 64 + q) * BK + rslot;

    f32x4 acc[8][4];
#pragma unroll
    for (int m = 0; m < 8; ++m)
#pragma unroll
        for (int n = 0; n < 4; ++n) acc[m][n] = 0.f;

    stage(0, 0);
    stage(1, 1);
    VMCNT(4);
    SCHEDB;
    BARRIER;
    SCHEDB;

    for (int kt = 0; kt < NKT; ++kt){
        int cur = kt & 1;
        s16x8 af[8], bq[4];
#pragma unroll
        for (int m = 0; m < 8; ++m) af[m] = *(const s16x8*)&As[cur][aoff + m * 16 * BK];
#pragma unroll
        for (int n = 0; n < 4; ++n) bq[n] = *(const s16x8*)&Bs[cur][boff + n * 16 * BK];

        __builtin_amdgcn_s_setprio(1);
#pragma unroll
        for (int m = 0; m < 8; ++m)
#pragma unroll
            for (int n = 0; n < 4; ++n)
                acc[m][n] = __builtin_amdgcn_mfma_f32_16x16x32_bf16(af[m], bq[n], acc[m][n], 0, 0, 0);
        __builtin_amdgcn_s_setprio(0);

        SCHEDB;
        LGKM0;
        BARRIER;
        SCHEDB;
        stage(cur, (kt + 2 < NKT) ? kt + 2 : NKT - 1);
        VMCNT(4);
        SCHEDB;
        BARRIER;
        SCHEDB;
    }
    VMCNT(0);

    // ---- epilogue with per-row batch-select qproj ----
    int o1 = off[gb * 4 + 1], o2 = off[gb * 4 + 2], o3 = off[gb * 4 + 3];
    float Vn[4], Q0[4], Q1[4], Q2[4], Q3[4];
#pragma unroll
    for (int n = 0; n < 4; ++n){
        int D = nt * BN + wn * 64 + n * 16 + q;
        Vn[n] = V[D];
        Q0[n] = qproj[(size_t)(gb * 4 + 0) * HDIM + D];
        Q1[n] = qproj[(size_t)(gb * 4 + 1) * HDIM + D];
        Q2[n] = qproj[(size_t)(gb * 4 + 2) * HDIM + D];
        Q3[n] = qproj[(size_t)(gb * 4 + 3) * HDIM + D];
    }
#pragma unroll
    for (int m = 0; m < 8; ++m){
#pragma unroll
        for (int r = 0; r < 4; ++r){
            int loc = mtl * BM + wm * 128 + m * 16 + lg * 4 + r;  // compact slot
            float s = 0.f;
#pragma unroll
            for (int n = 0; n < 4; ++n){
                float Qn = Q0[n];
                Qn = (loc >= o1) ? Q1[n] : Qn;
                Qn = (loc >= o2) ? Q2[n] : Qn;
                Qn = (loc >= o3) ? Q3[n] : Qn;
                float x = acc[m][n][r] + Qn;
                s += Vn[n] * tanh_fast(x);
            }
            s += __shfl_xor(s, 1);
            s += __shfl_xor(s, 2);
            s += __shfl_xor(s, 4);
            s += __shfl_xor(s, 8);
            if (q == 0)
                spart[((size_t)gb * GSEQ + loc) * 16 + nt * 4 + wn] = s;
        }
    }
}

// ---------------- softmax over S per batch (gathers group-compact spart) ---------
__global__ __launch_bounds__(256) void k_softmax(const float* __restrict__ spart,
                                                 const int* __restrict__ mask,
                                                 const int* __restrict__ pos,
                                                 float* __restrict__ attn){
    int b = blockIdx.x;
    int gb = b >> 2;
    int tid = threadIdx.x;
    int lane = tid & 63, wv = tid >> 6;
    __shared__ float redmx[4];
    __shared__ float redsm[4];

    float sc[8];
#pragma unroll
    for (int i = 0; i < 8; ++i){
        int s = i * 256 + tid;
        int mk = mask[(size_t)b * SEQ + s];
        if (mk != 0){
            int p = pos[(size_t)b * SEQ + s];    // slot within group
            const f32x4* pp = (const f32x4*)&spart[((size_t)gb * GSEQ + p) * 16];
            f32x4 v0 = pp[0], v1 = pp[1], v2 = pp[2], v3 = pp[3];
            sc[i] = (v0.x + v0.y + v0.z + v0.w) + (v1.x + v1.y + v1.z + v1.w)
                  + (v2.x + v2.y + v2.z + v2.w) + (v3.x + v3.y + v3.z + v3.w);
        } else {
            sc[i] = -1e9f;
        }
    }
    float mx = sc[0];
#pragma unroll
    for (int i = 1; i < 8; ++i) mx = fmaxf(mx, sc[i]);
#pragma unroll
    for (int o = 32; o >= 1; o >>= 1) mx = fmaxf(mx, __shfl_xor(mx, o));
    if (lane == 0) redmx[wv] = mx;
    __syncthreads();
    mx = fmaxf(fmaxf(redmx[0], redmx[1]), fmaxf(redmx[2], redmx[3]));

    float ex[8], ssum = 0.f;
#pragma unroll
    for (int i = 0; i < 8; ++i){
        ex[i] = __builtin_amdgcn_exp2f((sc[i] - mx) * 1.4426950408889634f);
        ssum += ex[i];
    }
#pragma unroll
    for (int o = 32; o >= 1; o >>= 1) ssum += __shfl_xor(ssum, o);
    if (lane == 0) redsm[wv] = ssum;
    __syncthreads();
    ssum = redsm[0] + redsm[1] + redsm[2] + redsm[3];
    float inv = 1.0f / ssum;
#pragma unroll
    for (int i = 0; i < 8; ++i)
        attn[(size_t)b * SEQ + i * 256 + tid] = ex[i] * inv;
}

// ---------------- context partials over this batch's compact span ----------------
__global__ __launch_bounds__(256) void k_ctxpart(const u16* __restrict__ keysbf,
                                                 const float* __restrict__ attn,
                                                 const int* __restrict__ cnt4,
                                                 const int* __restrict__ off,
                                                 const int* __restrict__ idx,
                                                 float* __restrict__ cpart){
    int blk = blockIdx.x;                 // 1024 = 32 b x 32 slices
    int b = blk >> 5, scn = blk & 31;
    int gb = b >> 2, j = b & 3;
    int oj  = off[gb * 4 + j];
    int oj1 = (j < 3) ? off[gb * 4 + j + 1] : cnt4[gb];
    int nb  = oj1 - oj;                   // rows of this batch
    int lim = nb - scn * 64;
    if (lim > 64) lim = 64;
    int t = threadIdx.x;
    f32x4 acc = 0.f;
    size_t base = (size_t)gb * GSEQ + oj + scn * 64;
    const s16x4* kp = (const s16x4*)(keysbf + base * HDIM) + t;
    const int* ip = idx + base;
    const float* ab = attn;               // flat [b][s] == group row gb*GSEQ+idxv
    for (int s = 0; s < lim; ++s){
        float a = ab[(size_t)gb * GSEQ + ip[s]];
        s16x4 kv = kp[(size_t)s * 256];
        f32x4 kf;
        kf.x = __uint_as_float((unsigned)(unsigned short)kv[0] << 16);
        kf.y = __uint_as_float((unsigned)(unsigned short)kv[1] << 16);
        kf.z = __uint_as_float((unsigned)(unsigned short)kv[2] << 16);
        kf.w = __uint_as_float((unsigned)(unsigned short)kv[3] << 16);
        acc += a * kf;
    }
    // always write (zeros when lim<=0) so ctxred sums no garbage
    *(f32x4*)&cpart[(size_t)(b * 32 + scn) * HDIM + t * 4] = acc;
}

__global__ __launch_bounds__(256) void k_ctxred(const float* __restrict__ cpart,
                                                float* __restrict__ ctx){
    int id = blockIdx.x * 256 + threadIdx.x;   // 128 blocks
    int b = id >> 10, h = id & 1023;
    float s = 0.f;
#pragma unroll
    for (int sc = 0; sc < 32; ++sc)
        s += cpart[(size_t)(b * 32 + sc) * HDIM + h];
    ctx[id] = s;
}

// ---------------- launch ---------------------------------------------------------
extern "C" void kernel_launch(void* const* d_in, const int* in_sizes, int n_in,
                              void* d_out, int out_size, void* d_ws, size_t ws_size,
                              hipStream_t stream){
    (void)in_sizes; (void)n_in; (void)out_size; (void)ws_size;
    const float* query = (const float*)d_in[0];
    const float* keys  = (const float*)d_in[1];
    const int*   mask  = (const int*)d_in[2];
    const float* W1    = (const float*)d_in[3];
    const float* W2    = (const float*)d_in[4];
    const float* V     = (const float*)d_in[5];

    float* ctx_out  = (float*)d_out;            // [32][1024]
    float* attn_out = ctx_out + BATCH * HDIM;   // [32][2048]

    char* ws = (char*)d_ws;
    u16*   W1T   = (u16*)ws;                                   // 2 MB   @ 0
    float* qproj = (float*)(ws + (2u << 20));                  // 128 KB @ 2M
    int*   cnt4  = (int*)  (ws + (2u << 20) + (128u << 10));   // 32 B
    int*   off   = (int*)  (ws + (2u << 20) + (132u << 10));   // 128 B
    int*   idx   = (int*)  (ws + (2u << 20) + (512u << 10));   // 256 KB @ 2.5M
    int*   pos   = (int*)  (ws + (3u << 20));                  // 256 KB @ 3M
    float* spart = (float*)(ws + (4u << 20));                  // 4 MB   @ 4M
    float* cpart = spart;   // reuse (spart dead after softmax)
    u16*   keysbf= (u16*)(ws + (9u << 20));                    // 128 MB @ 9M

    k_setup  <<<dim3(776),  dim3(256), 0, stream>>>(W1, W1T, query, W2, qproj,
                                                    mask, cnt4, off, idx, pos);
    k_gather <<<dim3(8192), dim3(256), 0, stream>>>(keys, cnt4, idx, keysbf);
    k_score  <<<dim3(1024), dim3(512), 0, stream>>>(keysbf, W1T, qproj, V,
                                                    cnt4, off, spart);
    k_softmax<<<dim3(32),   dim3(256), 0, stream>>>(spart, mask, pos, attn_out);
    k_ctxpart<<<dim3(1024), dim3(256), 0, stream>>>(keysbf, attn_out, cnt4, off,
                                                    idx, cpart);
    k_ctxred <<<dim3(128),  dim3(256), 0, stream>>>(cpart, ctx_out);
}